// Round 4
// baseline (388.803 us; speedup 1.0000x reference)
//
#include <hip/hip_runtime.h>
#include <math.h>

#define NEG_SLOPE 0.1f

constexpr int Bn = 512;
constexpr int Sn = 256;
constexpr int Dn = 256;

typedef short bf16x8 __attribute__((ext_vector_type(8)));
typedef float f32x4 __attribute__((ext_vector_type(4)));

__device__ inline ushort f2bf(float f) { // round-to-nearest-even bf16 bits
  uint u = __float_as_uint(f);
  uint r = u + 0x7FFFu + ((u >> 16) & 1u);
  return (ushort)(r >> 16);
}

// Raw barrier: drains LDS ops (cross-wave produce/consume) but NOT vmcnt —
// global prefetches stay in flight across it.
#define BAR() asm volatile("s_waitcnt lgkmcnt(0)\n\ts_barrier" ::: "memory")

// ---------------------------------------------------------------------------
// Kernel 0 (merged prep+vec): w1h = bf16(W1); vlr = {v_l, v_r, c_l, c_r}.
// ---------------------------------------------------------------------------
__global__ __launch_bounds__(256) void k_prep_vec(const float* __restrict__ w1,
                                                  const float* __restrict__ a_w,
                                                  const float* __restrict__ b1,
                                                  ushort* __restrict__ w1h,
                                                  float* __restrict__ vlr) {
  int idx = blockIdx.x * 256 + threadIdx.x;
  w1h[idx] = f2bf(w1[idx]);
  if (blockIdx.x < 8) {
    int d = threadIdx.x;
    int e0 = blockIdx.x * 32;
    float vl = 0.f, vr = 0.f;
    for (int e = e0; e < e0 + 32; ++e) {
      float w = w1[(size_t)e * 256 + d];
      vl += w * a_w[e];
      vr += w * a_w[256 + e];
    }
    atomicAdd(&vlr[d], vl);
    atomicAdd(&vlr[256 + d], vr);
    if (blockIdx.x == 0) {
      float pl = b1[d] * a_w[d], pr = b1[d] * a_w[256 + d];
#pragma unroll
      for (int o = 1; o < 64; o <<= 1) {
        pl += __shfl_xor(pl, o);
        pr += __shfl_xor(pr, o);
      }
      if ((threadIdx.x & 63) == 0) {
        atomicAdd(&vlr[512], pl);
        atomicAdd(&vlr[513], pr);
      }
    }
  }
}

// ---------------------------------------------------------------------------
// Fused kernel: one block per b (512 threads = 8 waves). LDS ~22 KB ->
// 2 blocks/CU co-resident (all 512 blocks in one round, 16 waves/CU).
// Phase A: Wh^T[b] (256x256 bf16) built via MFMA; fragments stored DIRECTLY
//          to block-private global scratch (L2-resident; scattered stores
//          write-combine). e_l/e_r in LDS.
// Phase B: 4 i-tiles x 4 j-chunks: scores->exp->ph (dbuf LDS) -> MFMA with
//          whT B-fragments read from global scratch (same-CU L2 hits) ->
//          normalize/ELU/store. Raw barriers; depth-2 pos prefetch.
// ---------------------------------------------------------------------------
__global__ __launch_bounds__(512) void k_fused(const float* __restrict__ x,
                                               const ushort* __restrict__ w1h,
                                               const float* __restrict__ b1,
                                               const float* __restrict__ vlr,
                                               const float* __restrict__ pos,
                                               const float* __restrict__ a_b,
                                               ushort* __restrict__ whT,
                                               float* __restrict__ out) {
  __shared__ __align__(16) ushort AhPh[9216]; // 18 KB union: Ah[2][64][72] | ph[2][64][72]
  __shared__ __align__(16) float vl_s[256];
  __shared__ __align__(16) float vr_s[256];
  __shared__ __align__(16) float el_s[256];
  __shared__ __align__(16) float er_s[256];
  __shared__ float rsum[64];

  const int t = threadIdx.x;
  const int wave = t >> 6, lane = t & 63;
  const int q = lane >> 4, c = lane & 15;
  const int b = blockIdx.x;

  const float cl = vlr[512], cr = vlr[513];
  const float ab = a_b[0];

  if (t < 256) {
    vl_s[t] = vlr[t];
    vr_s[t] = vlr[256 + t];
  }

  ushort* wb_w = whT + (size_t)b * 65536;

  // ---------------- Phase A ----------------
  const int g = wave >> 2;       // group 0/1 -> s-tiles {2g, 2g+1}
  const int wg = wave & 3;       // wave-in-group
  const int n0A = wg * 64;
  const int tt = t & 255;
  const int r = tt >> 2;         // staging row 0..63
  const int kq = (tt & 3) << 4;  // 0,16,32,48
  const float* xb = x + (size_t)b * 65536;
  ushort* Ahg = AhPh + g * 4608;

  float b1v[4];
#pragma unroll
  for (int nt = 0; nt < 4; ++nt) b1v[nt] = b1[n0A + nt * 16 + c];

  {
    f32x4 acc[4][4];
#pragma unroll
    for (int mi = 0; mi < 4; ++mi)
#pragma unroll
      for (int nt = 0; nt < 4; ++nt) acc[mi][nt] = (f32x4){0.f, 0.f, 0.f, 0.f};
    float sl = 0.f, sr = 0.f;

    float4 V0, V1, V2, V3, N0, N1, N2, N3;
    {
      const float* p = xb + (size_t)((g * 2) * 64 + r) * 256 + kq;
      V0 = *(const float4*)(p); V1 = *(const float4*)(p + 4);
      V2 = *(const float4*)(p + 8); V3 = *(const float4*)(p + 12);
    }

#pragma unroll
    for (int sk = 0; sk < 8; ++sk) {
      const int stile = g * 2 + (sk >> 2);
      const int k0 = (sk & 3) * 64;
      if (sk < 7) { // prefetch next k-step (rides across barriers)
        const int s2 = g * 2 + ((sk + 1) >> 2), kn = ((sk + 1) & 3) * 64;
        const float* p = xb + (size_t)(s2 * 64 + r) * 256 + kn + kq;
        N0 = *(const float4*)(p); N1 = *(const float4*)(p + 4);
        N2 = *(const float4*)(p + 8); N3 = *(const float4*)(p + 12);
      }
      BAR(); // prev MFMA's Ah reads drained (and vl_s visible, sk=0)
      {
        float vv[16] = {V0.x, V0.y, V0.z, V0.w, V1.x, V1.y, V1.z, V1.w,
                        V2.x, V2.y, V2.z, V2.w, V3.x, V3.y, V3.z, V3.w};
#pragma unroll
        for (int j = 0; j < 16; ++j) {
          sl += vv[j] * vl_s[k0 + kq + j];
          sr += vv[j] * vr_s[k0 + kq + j];
        }
#pragma unroll
        for (int j = 0; j < 4; ++j) {
          ushort4 h;
          ushort* hp = (ushort*)&h;
#pragma unroll
          for (int e = 0; e < 4; ++e) hp[e] = f2bf(vv[j * 4 + e]);
          *(ushort4*)&Ahg[r * 72 + kq + j * 4] = h;
        }
      }
      BAR(); // Ah visible

#pragma unroll
      for (int kk = 0; kk < 64; kk += 32) {
        bf16x8 bh[4];
#pragma unroll
        for (int nt = 0; nt < 4; ++nt)
          bh[nt] = *(const bf16x8*)(w1h + (size_t)(n0A + nt * 16 + c) * 256 + k0 + kk + q * 8);
#pragma unroll
        for (int mi = 0; mi < 4; ++mi) {
          bf16x8 ah = *(const bf16x8*)&Ahg[(mi * 16 + c) * 72 + kk + q * 8];
#pragma unroll
          for (int nt = 0; nt < 4; ++nt)
            acc[mi][nt] = __builtin_amdgcn_mfma_f32_16x16x32_bf16(ah, bh[nt], acc[mi][nt], 0, 0, 0);
        }
      }

      if ((sk & 3) == 3) { // end of one s-tile
        // e_l/e_r fp32 dots (exact): reduce 4 kq-quadrants
        sl += __shfl_xor(sl, 1); sl += __shfl_xor(sl, 2);
        sr += __shfl_xor(sr, 1); sr += __shfl_xor(sr, 2);
        if ((tt & 3) == 0) {
          el_s[stile * 64 + r] = sl + cl;
          er_s[stile * 64 + r] = sr + cr;
        }
        // fragment store acc+b1 -> global whT scratch (L2 write-combines;
        // block-private so no cross-block coherence needed)
#pragma unroll
        for (int mi = 0; mi < 4; ++mi)
#pragma unroll
          for (int nt = 0; nt < 4; ++nt) {
            ushort4 h;
            ushort* hp = (ushort*)&h;
#pragma unroll
            for (int reg = 0; reg < 4; ++reg) hp[reg] = f2bf(acc[mi][nt][reg] + b1v[nt]);
            *(ushort4*)&wb_w[(size_t)(n0A + nt * 16 + c) * 256 + stile * 64 + mi * 16 + q * 4] = h;
            acc[mi][nt] = (f32x4){0.f, 0.f, 0.f, 0.f};
          }
        sl = 0.f; sr = 0.f;
      }
      if (sk < 7) { V0 = N0; V1 = N1; V2 = N2; V3 = N3; }
    }
  }

  // ---------------- Phase boundary ----------------
  // Own whT stores retired (visible in this CU's L1/L2), then barrier => all
  // waves' stores visible before any wave reads whT.
  asm volatile("s_waitcnt vmcnt(0)" ::: "memory");

  const float* posb = pos + (size_t)b * 65536;
  // depth-2 pos prefetch: Pa = chunk 0, Pb = chunk 1 (issued before barrier,
  // in flight across it)
  float4 Pa0, Pa1, Pb0, Pb1, Pc0, Pc1;
  {
    const float* p0 = posb + (size_t)(wave * 8 + q) * 256 + c * 4;        // gc=0
    Pa0 = *(const float4*)p0; Pa1 = *(const float4*)(p0 + 1024);
    const float* p1 = posb + (size_t)(wave * 8 + q) * 256 + 64 + c * 4;   // gc=1
    Pb0 = *(const float4*)p1; Pb1 = *(const float4*)(p1 + 1024);
  }
  BAR(); // whT complete + el_s/er_s visible; AhPh free for ph

  // ---------------- Phase B ----------------
  const int n0B = wave * 32;
  const ushort* wb_r = whT + (size_t)b * 65536;
  f32x4 accB[4][2];
#pragma unroll
  for (int mi = 0; mi < 4; ++mi)
#pragma unroll
    for (int nt = 0; nt < 2; ++nt) accB[mi][nt] = (f32x4){0.f, 0.f, 0.f, 0.f};
  float psum0 = 0.f, psum1 = 0.f;

#pragma unroll
  for (int gc = 0; gc < 16; ++gc) {
    const int itile = gc >> 2, tc = gc & 3;
    if (gc < 14) { // prefetch chunk gc+2
      const int i2 = (gc + 2) >> 2, t2 = (gc + 2) & 3;
      const float* p = posb + (size_t)(i2 * 64 + wave * 8 + q) * 256 + t2 * 64 + c * 4;
      Pc0 = *(const float4*)p; Pc1 = *(const float4*)(p + 1024);
    }
    ushort* phb = AhPh + (gc & 1) * 4608;

    // scores for chunk gc (consume Pa)
    float4 er = *(const float4*)&er_s[tc * 64 + c * 4];
#pragma unroll
    for (int it2 = 0; it2 < 2; ++it2) {
      const int rl = wave * 8 + it2 * 4 + q;
      const float el = el_s[itile * 64 + rl];
      float4 pv = it2 ? Pa1 : Pa0;
      float s0 = el + er.x + ab; s0 = (s0 >= 0.f) ? s0 : NEG_SLOPE * s0; s0 += pv.x;
      float s1 = el + er.y + ab; s1 = (s1 >= 0.f) ? s1 : NEG_SLOPE * s1; s1 += pv.y;
      float s2 = el + er.z + ab; s2 = (s2 >= 0.f) ? s2 : NEG_SLOPE * s2; s2 += pv.z;
      float s3 = el + er.w + ab; s3 = (s3 >= 0.f) ? s3 : NEG_SLOPE * s3; s3 += pv.w;
      float e0 = __expf(s0), e1 = __expf(s1), e2 = __expf(s2), e3 = __expf(s3);
      if (it2) psum1 += e0 + e1 + e2 + e3; else psum0 += e0 + e1 + e2 + e3;
      ushort4 h;
      ushort* hp = (ushort*)&h;
      hp[0] = f2bf(e0); hp[1] = f2bf(e1); hp[2] = f2bf(e2); hp[3] = f2bf(e3);
      *(ushort4*)&phb[rl * 72 + c * 4] = h;
    }
    BAR(); // ph visible (prev buffer's MFMA reads drained at previous BAR)

    // MFMA: P-chunk @ WhT (global scratch, L2 hits)
#pragma unroll
    for (int kk = 0; kk < 64; kk += 32) {
      bf16x8 bfr[2];
#pragma unroll
      for (int nt = 0; nt < 2; ++nt)
        bfr[nt] = *(const bf16x8*)(wb_r + (size_t)(n0B + nt * 16 + c) * 256 + tc * 64 + kk + q * 8);
#pragma unroll
      for (int mi = 0; mi < 4; ++mi) {
        bf16x8 ah = *(const bf16x8*)&phb[(mi * 16 + c) * 72 + kk + q * 8];
#pragma unroll
        for (int nt = 0; nt < 2; ++nt)
          accB[mi][nt] = __builtin_amdgcn_mfma_f32_16x16x32_bf16(ah, bfr[nt], accB[mi][nt], 0, 0, 0);
      }
    }

    if (tc == 3) { // i-tile epilogue
      float p0v = psum0, p1v = psum1;
      p0v += __shfl_xor(p0v, 1); p0v += __shfl_xor(p0v, 2);
      p0v += __shfl_xor(p0v, 4); p0v += __shfl_xor(p0v, 8);
      p1v += __shfl_xor(p1v, 1); p1v += __shfl_xor(p1v, 2);
      p1v += __shfl_xor(p1v, 4); p1v += __shfl_xor(p1v, 8);
      if (c == 0) {
        rsum[wave * 8 + q] = p0v;
        rsum[wave * 8 + 4 + q] = p1v;
      }
      psum0 = 0.f; psum1 = 0.f;
      BAR(); // rsum visible
      float* outb = out + ((size_t)b * 256 + itile * 64) * 256;
#pragma unroll
      for (int mi = 0; mi < 4; ++mi) {
        float alpha[4];
#pragma unroll
        for (int reg = 0; reg < 4; ++reg) alpha[reg] = 1.0f / rsum[mi * 16 + q * 4 + reg];
#pragma unroll
        for (int nt = 0; nt < 2; ++nt)
#pragma unroll
          for (int reg = 0; reg < 4; ++reg) {
            float v = accB[mi][nt][reg] * alpha[reg];
            v = (v > 0.f) ? v : (__expf(v) - 1.0f);
            outb[(size_t)(mi * 16 + q * 4 + reg) * 256 + n0B + nt * 16 + c] = v;
            accB[mi][nt][reg] = 0.f;
          }
      }
    }
    Pa0 = Pb0; Pa1 = Pb1; Pb0 = Pc0; Pb1 = Pc1;
  }
}

// ---------------------------------------------------------------------------
extern "C" void kernel_launch(void* const* d_in, const int* in_sizes, int n_in,
                              void* d_out, int out_size, void* d_ws, size_t ws_size,
                              hipStream_t stream) {
  const float* x   = (const float*)d_in[0];
  const float* pos = (const float*)d_in[1];
  const float* w1  = (const float*)d_in[2];
  const float* b1  = (const float*)d_in[3];
  const float* a_w = (const float*)d_in[4];
  const float* a_b = (const float*)d_in[5];
  float* out = (float*)d_out;

  ushort* w1h = (ushort*)d_ws;                  // 65536 ushort (128 KB)
  ushort* whT = w1h + 65536;                    // 33554432 ushort (64 MB)
  float*  vlr = (float*)(whT + (size_t)33554432); // 514 floats

  hipMemsetAsync(vlr, 0, 514 * sizeof(float), stream);
  k_prep_vec<<<dim3(256), dim3(256), 0, stream>>>(w1, a_w, b1, w1h, vlr);
  k_fused<<<dim3(Bn), dim3(512), 0, stream>>>(x, w1h, b1, vlr, pos, a_b, whT, out);
}